// Round 5
// baseline (476.689 us; speedup 1.0000x reference)
//
#include <hip/hip_runtime.h>

// Problem constants (fixed by reference setup_inputs / RATE)
constexpr int B_ = 16;
constexpr int N_ = 2048;   // power of two: 2^11
constexpr int K_ = 1024;   // RATE * N

// Native 16B vector types (HIP's float4 is a class; the nontemporal builtins
// require native scalar/vector types).
typedef float  f32x4 __attribute__((ext_vector_type(4)));
typedef unsigned char u8x4 __attribute__((ext_vector_type(4)));

// ---------------------------------------------------------------------------
// Kernel 1: keep[b][n] = 1 iff score[b][n] is in the top-K_ of batch b.
// Exact jax.lax.top_k tie semantics: rank = #{m: s[m] > s[n]} + #{m<n: s[m]==s[n]},
// keep iff rank < K_. One block ranks 256 elements of one batch; the whole
// batch's 2048 scores sit in LDS. Inner index m is wave-uniform -> LDS
// broadcast, no bank conflicts.
// ---------------------------------------------------------------------------
__global__ __launch_bounds__(256) void topk_keep(const float* __restrict__ score,
                                                 unsigned char* __restrict__ keep) {
    __shared__ float s[N_];
    const int b     = blockIdx.x >> 3;   // N_/256 = 8 chunks per batch
    const int chunk = blockIdx.x & 7;
    const float* sb = score + b * N_;
    for (int t = threadIdx.x; t < N_; t += 256) s[t] = sb[t];
    __syncthreads();

    const int n   = (chunk << 8) + (int)threadIdx.x;
    const float v = s[n];
    int cnt = 0;
#pragma unroll 8
    for (int m = 0; m < N_; ++m) {
        const float u = s[m];
        cnt += (int)((u > v) | ((u == v) & (m < n)));
    }
    keep[b * N_ + n] = (cnt < K_) ? (unsigned char)1 : (unsigned char)0;
}

// ---------------------------------------------------------------------------
// Kernel 2: out[b,i,j] = (keep[b,i] || keep[b,j]) ? adj[b,i,j] : 0
// Grid-stride over half-rows (256 f32x4s each). keep[row] is block-uniform
// per iteration -> scalarized load + non-divergent branch; kept rows are a
// pure 16B copy (no kj loads). adj/out are touch-once 256 MiB streams ->
// nontemporal. 2048 blocks x 32 half-rows each amortizes launch overhead.
// ---------------------------------------------------------------------------
__global__ __launch_bounds__(256) void apply_mask(const f32x4* __restrict__ adj,
                                                  const unsigned char* __restrict__ keep,
                                                  f32x4* __restrict__ out) {
    constexpr int HALF_ROWS = B_ * N_ * 2;                 // 65536
    const int tid = (int)threadIdx.x;
    for (int hr = (int)blockIdx.x; hr < HALF_ROWS; hr += (int)gridDim.x) {
        const int row = hr >> 1;                            // 0 .. B_*N_-1
        const int j4  = ((hr & 1) << 8) + tid;              // 0..511
        const long long v = ((long long)row << 9) + j4;     // f32x4 index

        const f32x4 a = __builtin_nontemporal_load(adj + v);

        if (keep[row]) {                                    // block-uniform branch
            __builtin_nontemporal_store(a, out + v);
            continue;
        }

        const int b = row >> 11;                            // batch
        const u8x4 kj = *reinterpret_cast<const u8x4*>(keep + (b << 11) + (j4 << 2));
        f32x4 o;
        o.x = kj.x ? a.x : 0.0f;
        o.y = kj.y ? a.y : 0.0f;
        o.z = kj.z ? a.z : 0.0f;
        o.w = kj.w ? a.w : 0.0f;
        __builtin_nontemporal_store(o, out + v);
    }
}

extern "C" void kernel_launch(void* const* d_in, const int* in_sizes, int n_in,
                              void* d_out, int out_size, void* d_ws, size_t ws_size,
                              hipStream_t stream) {
    const float* adj   = (const float*)d_in[0];   // [B, N, N] f32
    const float* score = (const float*)d_in[1];   // [B, N, 1] f32
    float* out         = (float*)d_out;           // [B, N, N] f32
    unsigned char* keep = (unsigned char*)d_ws;   // B_*N_ = 32 KB scratch

    // 1) top-k membership mask (exact, tie-break by lower index)
    topk_keep<<<B_ * (N_ / 256), 256, 0, stream>>>(score, keep);

    // 2) streaming masked copy: grid-stride over half-rows
    apply_mask<<<2048, 256, 0, stream>>>((const f32x4*)adj, keep, (f32x4*)out);
}